// Round 1
// baseline (1696.425 us; speedup 1.0000x reference)
//
#include <hip/hip_runtime.h>
#include <math.h>

// Softmax splatting: B=8, C=4, H=512, W=960, fp32.
// d_out [B,C,H,W] doubles as the numerator accumulator.
// d_ws first B*H*W floats = weight-channel accumulator (needs 15.7 MB of ws).

#define EPS 1e-7f

constexpr int B = 8, C = 4, H = 512, W = 960;
constexpr int HW = H * W;            // 491520
constexpr int CHW = C * HW;          // 1966080
constexpr int NPIX = B * HW;         // 3932160

__global__ __launch_bounds__(256) void splat_kernel(
    const float* __restrict__ frame,
    const float* __restrict__ flow,
    const float* __restrict__ imp,
    float* __restrict__ acc,    // [B,C,H,W] numerator accumulator (= d_out)
    float* __restrict__ wacc)   // [B,H,W]   weight accumulator (in d_ws)
{
    int idx = blockIdx.x * blockDim.x + threadIdx.x;
    if (idx >= NPIX) return;
    int b = idx / HW;
    int p = idx - b * HW;
    int y = p / W;
    int x = p - y * W;

    const float fl_x = flow[(size_t)b * 2 * HW + p];
    const float fl_y = flow[(size_t)b * 2 * HW + HW + p];
    const float im   = expf(imp[(size_t)b * HW + p]);

    float tx = (float)x + fl_x;
    float ty = (float)y + fl_y;
    float fxf = floorf(tx);
    float fyf = floorf(ty);
    float dx = tx - fxf;
    float dy = ty - fyf;
    int fx = (int)fxf;
    int fy = (int)fyf;

    size_t fbase = (size_t)b * CHW + p;
    float f0 = frame[fbase + 0 * HW] * im;
    float f1 = frame[fbase + 1 * HW] * im;
    float f2 = frame[fbase + 2 * HW] * im;
    float f3 = frame[fbase + 3 * HW] * im;

    #pragma unroll
    for (int cyi = 0; cyi < 2; ++cyi) {
        #pragma unroll
        for (int cxi = 0; cxi < 2; ++cxi) {
            int cx = fx + cxi;
            int cy = fy + cyi;
            float w = (cxi ? dx : 1.0f - dx) * (cyi ? dy : 1.0f - dy);
            if (cx >= 0 && cx < W && cy >= 0 && cy < H) {
                size_t o = (size_t)b * CHW + (size_t)cy * W + cx;
                atomicAdd(&acc[o + 0 * HW], f0 * w);
                atomicAdd(&acc[o + 1 * HW], f1 * w);
                atomicAdd(&acc[o + 2 * HW], f2 * w);
                atomicAdd(&acc[o + 3 * HW], f3 * w);
                atomicAdd(&wacc[(size_t)b * HW + (size_t)cy * W + cx], im * w);
            }
        }
    }
}

__global__ __launch_bounds__(256) void norm_kernel(
    float* __restrict__ acc,
    const float* __restrict__ wacc)
{
    int idx = blockIdx.x * blockDim.x + threadIdx.x;
    if (idx >= NPIX) return;
    int b = idx / HW;
    int p = idx - b * HW;
    float inv = 1.0f / (wacc[(size_t)b * HW + p] + EPS);
    size_t o = (size_t)b * CHW + p;
    acc[o + 0 * HW] *= inv;
    acc[o + 1 * HW] *= inv;
    acc[o + 2 * HW] *= inv;
    acc[o + 3 * HW] *= inv;
}

extern "C" void kernel_launch(void* const* d_in, const int* in_sizes, int n_in,
                              void* d_out, int out_size, void* d_ws, size_t ws_size,
                              hipStream_t stream) {
    const float* frame = (const float*)d_in[0];
    const float* flow  = (const float*)d_in[1];
    const float* imp   = (const float*)d_in[2];
    float* acc  = (float*)d_out;
    float* wacc = (float*)d_ws;

    // zero the accumulators every call (harness poisons once, we re-zero)
    hipMemsetAsync(acc, 0, (size_t)out_size * sizeof(float), stream);
    hipMemsetAsync(wacc, 0, (size_t)NPIX * sizeof(float), stream);

    int threads = 256;
    int blocks = (NPIX + threads - 1) / threads;
    splat_kernel<<<blocks, threads, 0, stream>>>(frame, flow, imp, acc, wacc);
    norm_kernel<<<blocks, threads, 0, stream>>>(acc, wacc);
}

// Round 2
// 499.990 us; speedup vs baseline: 3.3929x; 3.3929x over previous
//
#include <hip/hip_runtime.h>
#include <math.h>

// Softmax splatting: B=8, C=4, H=512, W=960, fp32.
// d_out [B,C,H,W] doubles as the numerator accumulator.
// d_ws first B*H*W floats = weight-channel accumulator (15.7 MB).

#define EPS 1e-7f

constexpr int B = 8, C = 4, H = 512, W = 960;
constexpr int HW = H * W;            // 491520
constexpr int CHW = C * HW;          // 1966080
constexpr int NPIX = B * HW;         // 3932160

constexpr int TX = 32, TY = 32;      // source tile
constexpr int HALO = 6;              // |flow| < 6 handled in LDS (N(0,1): always)
constexpr int EX = TX + 2 * HALO;    // 44
constexpr int EY = TY + 2 * HALO;    // 44
constexpr int ECELLS = EX * EY;      // 1936

__global__ __launch_bounds__(256) void splat_kernel(
    const float* __restrict__ frame,
    const float* __restrict__ flow,
    const float* __restrict__ imp,
    float* __restrict__ acc,    // [B,C,H,W] numerator accumulator (= d_out)
    float* __restrict__ wacc)   // [B,H,W]   weight accumulator (in d_ws)
{
    __shared__ float lacc[5][EY][EX];   // 38720 B

    const int tid = threadIdx.x;
    const int tile_x0 = blockIdx.x * TX;
    const int tile_y0 = blockIdx.y * TY;
    const int b = blockIdx.z;

    // zero LDS accumulator
    float* lflat = &lacc[0][0][0];
    for (int i = tid; i < 5 * ECELLS; i += 256) lflat[i] = 0.0f;
    __syncthreads();

    const size_t fb_base = (size_t)b * CHW;
    const size_t fl_base = (size_t)b * 2 * HW;
    const size_t im_base = (size_t)b * HW;

    // each thread handles 4 source pixels of the 32x32 tile
    #pragma unroll
    for (int sub = 0; sub < 4; ++sub) {
        int pi = tid + sub * 256;           // 0..1023
        int sy = pi >> 5;                   // /32
        int sx = pi & 31;
        int x = tile_x0 + sx;
        int y = tile_y0 + sy;
        int p = y * W + x;

        float fl_x = flow[fl_base + p];
        float fl_y = flow[fl_base + HW + p];
        float im   = expf(imp[im_base + p]);

        float tx = (float)x + fl_x;
        float ty = (float)y + fl_y;
        float fxf = floorf(tx);
        float fyf = floorf(ty);
        float dx = tx - fxf;
        float dy = ty - fyf;
        int fx = (int)fxf;
        int fy = (int)fyf;

        float f0 = frame[fb_base + 0 * HW + p] * im;
        float f1 = frame[fb_base + 1 * HW + p] * im;
        float f2 = frame[fb_base + 2 * HW + p] * im;
        float f3 = frame[fb_base + 3 * HW + p] * im;

        #pragma unroll
        for (int cyi = 0; cyi < 2; ++cyi) {
            #pragma unroll
            for (int cxi = 0; cxi < 2; ++cxi) {
                int cx = fx + cxi;
                int cy = fy + cyi;
                float w = (cxi ? dx : 1.0f - dx) * (cyi ? dy : 1.0f - dy);
                int lx = cx - tile_x0 + HALO;
                int ly = cy - tile_y0 + HALO;
                if ((unsigned)lx < (unsigned)EX && (unsigned)ly < (unsigned)EY) {
                    int cell = ly * EX + lx;
                    atomicAdd(&lflat[0 * ECELLS + cell], f0 * w);
                    atomicAdd(&lflat[1 * ECELLS + cell], f1 * w);
                    atomicAdd(&lflat[2 * ECELLS + cell], f2 * w);
                    atomicAdd(&lflat[3 * ECELLS + cell], f3 * w);
                    atomicAdd(&lflat[4 * ECELLS + cell], im * w);
                } else if ((unsigned)cx < (unsigned)W && (unsigned)cy < (unsigned)H) {
                    // outlier flow: direct global fallback (statistically never)
                    size_t o = fb_base + (size_t)cy * W + cx;
                    atomicAdd(&acc[o + 0 * HW], f0 * w);
                    atomicAdd(&acc[o + 1 * HW], f1 * w);
                    atomicAdd(&acc[o + 2 * HW], f2 * w);
                    atomicAdd(&acc[o + 3 * HW], f3 * w);
                    atomicAdd(&wacc[im_base + (size_t)cy * W + cx], im * w);
                }
            }
        }
    }

    __syncthreads();

    // flush LDS tile to global with distinct-address coalesced atomics
    for (int i = tid; i < ECELLS; i += 256) {
        int ly = i / EX;
        int lx = i - ly * EX;
        int gy = tile_y0 - HALO + ly;
        int gx = tile_x0 - HALO + lx;
        if ((unsigned)gx >= (unsigned)W || (unsigned)gy >= (unsigned)H) continue;
        float wv = lflat[4 * ECELLS + i];
        if (wv == 0.0f) continue;   // nothing splatted here (imp>0 => wv>0 iff any contribution)
        size_t o = fb_base + (size_t)gy * W + gx;
        atomicAdd(&acc[o + 0 * HW], lflat[0 * ECELLS + i]);
        atomicAdd(&acc[o + 1 * HW], lflat[1 * ECELLS + i]);
        atomicAdd(&acc[o + 2 * HW], lflat[2 * ECELLS + i]);
        atomicAdd(&acc[o + 3 * HW], lflat[3 * ECELLS + i]);
        atomicAdd(&wacc[im_base + (size_t)gy * W + gx], wv);
    }
}

__global__ __launch_bounds__(256) void norm_kernel(
    float* __restrict__ acc,
    const float* __restrict__ wacc)
{
    int idx = blockIdx.x * blockDim.x + threadIdx.x;
    if (idx >= NPIX) return;
    int b = idx / HW;
    int p = idx - b * HW;
    float inv = 1.0f / (wacc[(size_t)b * HW + p] + EPS);
    size_t o = (size_t)b * CHW + p;
    acc[o + 0 * HW] *= inv;
    acc[o + 1 * HW] *= inv;
    acc[o + 2 * HW] *= inv;
    acc[o + 3 * HW] *= inv;
}

extern "C" void kernel_launch(void* const* d_in, const int* in_sizes, int n_in,
                              void* d_out, int out_size, void* d_ws, size_t ws_size,
                              hipStream_t stream) {
    const float* frame = (const float*)d_in[0];
    const float* flow  = (const float*)d_in[1];
    const float* imp   = (const float*)d_in[2];
    float* acc  = (float*)d_out;
    float* wacc = (float*)d_ws;

    hipMemsetAsync(acc, 0, (size_t)out_size * sizeof(float), stream);
    hipMemsetAsync(wacc, 0, (size_t)NPIX * sizeof(float), stream);

    dim3 grid(W / TX, H / TY, B);   // 30 x 16 x 8
    splat_kernel<<<grid, 256, 0, stream>>>(frame, flow, imp, acc, wacc);

    int threads = 256;
    int blocks = (NPIX + threads - 1) / threads;
    norm_kernel<<<blocks, threads, 0, stream>>>(acc, wacc);
}

// Round 3
// 419.237 us; speedup vs baseline: 4.0465x; 1.1926x over previous
//
#include <hip/hip_runtime.h>
#include <math.h>

// Softmax splatting: B=8, C=4, H=512, W=960, fp32.
// Owner-computes: each block owns a 32x32 OUTPUT tile, gathers all sources
// within +-RAD, scatters their corners into an LDS accumulator (only corners
// inside its own tile), then normalizes and stores directly. No global
// atomics except the rare overflow path (|flow| > RAD ~ never for N(0,1)).

#define EPS 1e-7f

constexpr int B = 8, C = 4, H = 512, W = 960;
constexpr int HW = H * W;            // 491520
constexpr int CHW = C * HW;          // 1966080
constexpr int NPIX = B * HW;         // 3932160

constexpr int TX = 32, TY = 32;      // output tile
constexpr int RAD = 5;               // coverage box half-width (|corner-src| <= RAD)
constexpr int RX = TX + 2 * RAD;     // 42: source region width
constexpr int RY = TY + 2 * RAD;     // 42
constexpr int RCELLS = RX * RY;      // 1764

constexpr int OVF_CAP = 480000;      // 480K entries * 32B = 15.36 MB in d_ws

// ---- prepass: sources whose corners escape the +-RAD box -> overflow list
__global__ __launch_bounds__(256) void outlier_pass(
    const float* __restrict__ frame,
    const float* __restrict__ flow,
    const float* __restrict__ imp,
    int* __restrict__ ovf_cnt,
    float* __restrict__ ovf_buf)
{
    int idx = blockIdx.x * blockDim.x + threadIdx.x;
    if (idx >= NPIX) return;
    int b = idx / HW;
    int p = idx - b * HW;
    int sy = p / W;
    int sx = p - sy * W;

    const size_t flb = (size_t)b * 2 * HW;
    float flx = flow[flb + p];
    float fly = flow[flb + HW + p];

    // fast reject: |fl| <= RAD-1 guarantees both corners within +-RAD box
    if (fabsf(flx) <= (float)(RAD - 1) && fabsf(fly) <= (float)(RAD - 1)) return;

    float tx = (float)sx + flx;
    float ty = (float)sy + fly;
    float fxf = floorf(tx);
    float fyf = floorf(ty);
    float dx = tx - fxf;
    float dy = ty - fyf;
    int fx = (int)fxf;
    int fy = (int)fyf;

    const size_t fb = (size_t)b * CHW;
    float im = __expf(imp[(size_t)b * HW + p]);
    float f0 = frame[fb + 0 * HW + p] * im;
    float f1 = frame[fb + 1 * HW + p] * im;
    float f2 = frame[fb + 2 * HW + p] * im;
    float f3 = frame[fb + 3 * HW + p] * im;

    #pragma unroll
    for (int cyi = 0; cyi < 2; ++cyi) {
        #pragma unroll
        for (int cxi = 0; cxi < 2; ++cxi) {
            int cx = fx + cxi;
            int cy = fy + cyi;
            if ((unsigned)cx >= (unsigned)W || (unsigned)cy >= (unsigned)H) continue;
            int ax = cx - sx; if (ax < 0) ax = -ax;
            int ay = cy - sy; if (ay < 0) ay = -ay;
            if (ax <= RAD && ay <= RAD) continue;   // covered by owner block
            float w = (cxi ? dx : 1.0f - dx) * (cyi ? dy : 1.0f - dy);
            int e = atomicAdd(ovf_cnt, 1);
            if (e < OVF_CAP) {
                float* ent = ovf_buf + (size_t)e * 8;
                ent[0] = __int_as_float(b * HW + cy * W + cx);
                ent[1] = f0 * w;
                ent[2] = f1 * w;
                ent[3] = f2 * w;
                ent[4] = f3 * w;
                ent[5] = im * w;
            }
        }
    }
}

// ---- main: per-output-tile gather-scatter + fused normalize
__global__ __launch_bounds__(256) void splat_main(
    const float* __restrict__ frame,
    const float* __restrict__ flow,
    const float* __restrict__ imp,
    float* __restrict__ out,
    const int* __restrict__ ovf_cnt,
    const float* __restrict__ ovf_buf)
{
    __shared__ float lacc[5][TY][TX];   // 20480 B -> 8 blocks/CU

    const int tid = threadIdx.x;
    const int x0 = blockIdx.x * TX;
    const int y0 = blockIdx.y * TY;
    const int b  = blockIdx.z;

    float* lf = &lacc[0][0][0];
    for (int i = tid; i < 5 * TX * TY; i += 256) lf[i] = 0.0f;
    __syncthreads();

    const size_t fb  = (size_t)b * CHW;
    const size_t flb = (size_t)b * 2 * HW;
    const size_t ib  = (size_t)b * HW;

    // scatter: all sources whose +-RAD coverage box can touch my tile
    for (int i = tid; i < RCELLS; i += 256) {
        int ly = i / RX;
        int lx = i - ly * RX;
        int sx = x0 - RAD + lx;
        int sy = y0 - RAD + ly;
        if ((unsigned)sx >= (unsigned)W || (unsigned)sy >= (unsigned)H) continue;
        int p = sy * W + sx;

        float flx = flow[flb + p];
        float fly = flow[flb + HW + p];
        float im  = __expf(imp[ib + p]);

        float tx = (float)sx + flx;
        float ty = (float)sy + fly;
        float fxf = floorf(tx);
        float fyf = floorf(ty);
        float dx = tx - fxf;
        float dy = ty - fyf;
        int fx = (int)fxf;
        int fy = (int)fyf;

        float f0 = frame[fb + 0 * HW + p] * im;
        float f1 = frame[fb + 1 * HW + p] * im;
        float f2 = frame[fb + 2 * HW + p] * im;
        float f3 = frame[fb + 3 * HW + p] * im;

        #pragma unroll
        for (int cyi = 0; cyi < 2; ++cyi) {
            #pragma unroll
            for (int cxi = 0; cxi < 2; ++cxi) {
                int cx = fx + cxi;
                int cy = fy + cyi;
                int lxc = cx - x0;
                int lyc = cy - y0;
                if ((unsigned)lxc >= (unsigned)TX || (unsigned)lyc >= (unsigned)TY) continue;
                int ax = cx - sx; if (ax < 0) ax = -ax;
                int ay = cy - sy; if (ay < 0) ay = -ay;
                if (ax > RAD || ay > RAD) continue;     // overflow list handles
                float w = (cxi ? dx : 1.0f - dx) * (cyi ? dy : 1.0f - dy);
                int cell = lyc * TX + lxc;
                atomicAdd(&lf[0 * 1024 + cell], f0 * w);
                atomicAdd(&lf[1 * 1024 + cell], f1 * w);
                atomicAdd(&lf[2 * 1024 + cell], f2 * w);
                atomicAdd(&lf[3 * 1024 + cell], f3 * w);
                atomicAdd(&lf[4 * 1024 + cell], im * w);
            }
        }
    }

    // merge overflow entries that land in my tile
    int cnt = *ovf_cnt;
    if (cnt > OVF_CAP) cnt = OVF_CAP;
    for (int e = tid; e < cnt; e += 256) {
        const float* ent = ovf_buf + (size_t)e * 8;
        int bcell = __float_as_int(ent[0]);
        int eb = bcell / HW;
        if (eb != b) continue;
        int rem = bcell - eb * HW;
        int cy = rem / W;
        int cx = rem - cy * W;
        int lxc = cx - x0;
        int lyc = cy - y0;
        if ((unsigned)lxc >= (unsigned)TX || (unsigned)lyc >= (unsigned)TY) continue;
        int cell = lyc * TX + lxc;
        atomicAdd(&lf[0 * 1024 + cell], ent[1]);
        atomicAdd(&lf[1 * 1024 + cell], ent[2]);
        atomicAdd(&lf[2 * 1024 + cell], ent[3]);
        atomicAdd(&lf[3 * 1024 + cell], ent[4]);
        atomicAdd(&lf[4 * 1024 + cell], ent[5]);
    }

    __syncthreads();

    // fused normalize + store (writes every output pixel exactly once)
    for (int i = tid; i < TX * TY; i += 256) {
        int cy = i >> 5;
        int cx = i & 31;
        float inv = 1.0f / (lacc[4][cy][cx] + EPS);
        size_t o = fb + (size_t)(y0 + cy) * W + (x0 + cx);
        out[o + 0 * HW] = lacc[0][cy][cx] * inv;
        out[o + 1 * HW] = lacc[1][cy][cx] * inv;
        out[o + 2 * HW] = lacc[2][cy][cx] * inv;
        out[o + 3 * HW] = lacc[3][cy][cx] * inv;
    }
}

extern "C" void kernel_launch(void* const* d_in, const int* in_sizes, int n_in,
                              void* d_out, int out_size, void* d_ws, size_t ws_size,
                              hipStream_t stream) {
    const float* frame = (const float*)d_in[0];
    const float* flow  = (const float*)d_in[1];
    const float* imp   = (const float*)d_in[2];
    float* out = (float*)d_out;

    int*   ovf_cnt = (int*)d_ws;
    float* ovf_buf = (float*)((char*)d_ws + 16);

    hipMemsetAsync(d_ws, 0, 16, stream);   // just the counter

    outlier_pass<<<(NPIX + 255) / 256, 256, 0, stream>>>(frame, flow, imp, ovf_cnt, ovf_buf);

    dim3 grid(W / TX, H / TY, B);   // 30 x 16 x 8
    splat_main<<<grid, 256, 0, stream>>>(frame, flow, imp, out, ovf_cnt, ovf_buf);
}